// Round 18
// baseline (277.596 us; speedup 1.0000x reference)
//
#include <hip/hip_runtime.h>
#include <math.h>

#define NN 100000
#define NE 3200000
#define NR 90
#define NB 391          // buckets of 256 nodes (dst>>8)
#define CH 4096         // edges per block in pass1
#define NCHUNK 782      // ceil(NE/CH)
#define CAP 12288       // padded per-bucket capacity (mean 8192, +45 sigma)

typedef unsigned int u32;
typedef unsigned short u16;

__device__ inline u32 pack2(float a, float b) {       // bf16(a) lo16, bf16(b) hi16 (RNE)
    u32 ua = __float_as_uint(a); ua += 0x7FFFu + ((ua >> 16) & 1u);
    u32 ub = __float_as_uint(b); ub += 0x7FFFu + ((ub >> 16) & 1u);
    return (ua >> 16) | (ub & 0xFFFF0000u);
}
__device__ inline float unlo(u32 w) { return __uint_as_float(w << 16); }
__device__ inline float unhi(u32 w) { return __uint_as_float(w & 0xFFFF0000u); }

// ---------------- pass 1: direct padded-bucket partition (no pre-count) ----------------
// tmp entry: (dst&255)<<24 | src<<7 | et ; bucket b's window is tmp[b*CAP ..]
__global__ __launch_bounds__(512) void pass1_kernel(const int* __restrict__ src,
                                                    const int* __restrict__ dst,
                                                    const int* __restrict__ et,
                                                    u32* __restrict__ ccursor,
                                                    u32* __restrict__ tmp) {
    __shared__ u32 cntA[NB];
    __shared__ u32 lcur[NB];
    __shared__ u32 delta[NB];
    __shared__ u32 scanS[512];
    __shared__ u32 lrecs[CH];
    __shared__ u16 lbid[CH];
    int tid = threadIdx.x;
    int c0 = blockIdx.x * CH;
    int c1 = c0 + CH; if (c1 > NE) c1 = NE;
    int nloc = c1 - c0;

    if (tid < NB) cntA[tid] = 0;
    __syncthreads();

    for (int e = c0 + tid; e < c1; e += 512)
        atomicAdd(&cntA[(u32)dst[e] >> 8], 1u);
    __syncthreads();

    scanS[tid] = (tid < NB) ? cntA[tid] : 0u;
    __syncthreads();
#pragma unroll
    for (int ofs = 1; ofs < 512; ofs <<= 1) {
        u32 v = (tid >= ofs) ? scanS[tid - ofs] : 0u;
        __syncthreads();
        scanS[tid] += v;
        __syncthreads();
    }
    if (tid < NB) {
        u32 excl = (tid == 0) ? 0u : scanS[tid - 1];
        lcur[tid] = excl;
        u32 c = cntA[tid];
        delta[tid] = c ? ((u32)tid * CAP + atomicAdd(&ccursor[tid], c) - excl) : 0u;
    }
    __syncthreads();

    for (int e = c0 + tid; e < c1; e += 512) {
        u32 d = (u32)dst[e];
        u32 b = d >> 8;
        u32 pos = atomicAdd(&lcur[b], 1u);
        lrecs[pos] = ((d & 255u) << 24) | ((u32)src[e] << 7) | (u32)et[e];
        lbid[pos] = (u16)b;
    }
    __syncthreads();

    for (int k = tid; k < nloc; k += 512)
        tmp[delta[lbid[k]] + k] = lrecs[k];
}

// ---------------- pass 2 + layer 1 fused (1024 threads/block) ----------------
// A': per-(node,rel) counts (1 LDS atomic/edge); degrees derived by byte-summing;
// C: scatter with cursor atomic only; D: embed count byte; E: layer1.
__global__ __launch_bounds__(1024) void pass2_kernel(const u32* __restrict__ tmp,
                                                     const u32* __restrict__ ccursor,
                                                     uint2* __restrict__ off2,
                                                     u32* __restrict__ recs,
                                                     const float* __restrict__ x,
                                                     const float* __restrict__ w1,
                                                     const float* __restrict__ root1,
                                                     const float* __restrict__ b1,
                                                     uint4* __restrict__ h1b) {
    __shared__ u32 lc2[256];         // per-node cursor (relative)
    __shared__ u32 cnt32[256 * 23];  // per-(node,rel) u8 counts packed 4/word
    __shared__ u32 sh[256];          // inclusive degree scan (survives all phases)
    int tid = threadIdx.x;
    int b = blockIdx.x;
    u32 r0 = (u32)b * CAP;
    u32 r1 = r0 + ccursor[b];        // cursor's final value == bucket edge count

    for (int i = tid; i < 256 * 23; i += 1024) cnt32[i] = 0;
    __syncthreads();

    // A': per-(node,rel) counts — single LDS atomic per edge
    for (u32 k = r0 + tid; k < r1; k += 1024) {
        u32 v = tmp[k];
        u32 ln = v >> 24;
        u32 rel = v & 127u;
        atomicAdd(&cnt32[ln * 23 + (rel >> 2)], 1u << ((rel & 3u) * 8u));
    }
    __syncthreads();

    // A2: per-node degree = bytewise sum of own 23-word slice (no atomics)
    if (tid < 256) {
        u32 s = 0;
#pragma unroll
        for (int i = 0; i < 23; i++) {
            u32 w = cnt32[tid * 23 + i];
            s += (w & 255u) + ((w >> 8) & 255u) + ((w >> 16) & 255u) + (w >> 24);
        }
        sh[tid] = s;
    }
    __syncthreads();

    // B: inclusive scan of degrees (256 entries)
#pragma unroll
    for (int ofs = 1; ofs < 256; ofs <<= 1) {
        u32 v = (tid >= ofs && tid < 256) ? sh[tid - ofs] : 0u;
        __syncthreads();
        if (tid < 256) sh[tid] += v;
        __syncthreads();
    }
    int n = b * 256 + tid;
    if (tid < 256) {
        u32 excl = (tid == 0) ? 0u : sh[tid - 1];
        if (n < NN) off2[n] = make_uint2(r0 + excl, r0 + sh[tid]);
        lc2[tid] = excl;
    }
    __syncthreads();

    // C: fine scatter — cursor atomic only
    for (u32 k = r0 + tid; k < r1; k += 1024) {
        u32 v = tmp[k];
        u32 ln = v >> 24;
        u32 pos = atomicAdd(&lc2[ln], 1u);
        recs[r0 + pos] = v & 0xFFFFFFu;
    }
    __syncthreads();

    // D: embed per-(node,rel) count into top byte of each rec
    if (tid < 256 && n < NN) {
        u32 start = (tid == 0) ? 0u : sh[tid - 1];
        u32 end = sh[tid];
        for (u32 j = start; j < end; j++) {
            u32 rel = recs[r0 + j] & 127u;
            u32 c = (cnt32[tid * 23 + (rel >> 2)] >> ((rel & 3u) * 8u)) & 255u;
            recs[r0 + j] |= c << 24;
        }
    }
    __syncthreads();

    // E: layer 1 for this bucket's 256 nodes — 8 lanes/node, 2 sweeps of 128 nodes
#pragma unroll
    for (int g = 0; g < 2; g++) {
        int ln = g * 128 + (tid >> 3);         // 0..255
        int r = tid & 7;
        int nn = b * 256 + ln;
        float acc[8];
#pragma unroll
        for (int j = 0; j < 8; j++) acc[j] = 0.0f;
        if (nn < NN) {
            u32 k0 = r0 + ((ln == 0) ? 0u : sh[ln - 1]);
            u32 k1 = r0 + sh[ln];
            for (u32 k = k0 + r; k < k1; k += 8) {
                u32 rec = recs[k];
                u32 t = rec & 127u, s = (rec >> 7) & 0x1FFFFu;
                float norm = 1.0f / (float)(rec >> 24);
                float4 xv = *(const float4*)(x + (size_t)s * 4);
                float x0 = xv.x * norm, x1 = xv.y * norm;
                float x2 = xv.z * norm, x3 = xv.w * norm;
                const float* w = w1 + (size_t)t * 16;   // [2][2][4]
#pragma unroll
                for (int o = 0; o < 4; o++) {
                    acc[o]     += x0 * w[o]     + x1 * w[4 + o];
                    acc[4 + o] += x2 * w[8 + o] + x3 * w[12 + o];
                }
            }
        }
#pragma unroll
        for (int j = 0; j < 8; j++) {
            acc[j] += __shfl_xor(acc[j], 1);
            acc[j] += __shfl_xor(acc[j], 2);
            acc[j] += __shfl_xor(acc[j], 4);
        }
        if (r == 0 && nn < NN) {
            float4 xn = *(const float4*)(x + (size_t)nn * 4);
            float h[8];
#pragma unroll
            for (int j = 0; j < 8; j++) {
                float v = acc[j] + b1[j] + xn.x * root1[j] + xn.y * root1[8 + j]
                        + xn.z * root1[16 + j] + xn.w * root1[24 + j];
                h[j] = fmaxf(v, 0.0f);
            }
            h1b[nn] = make_uint4(pack2(h[0], h[1]), pack2(h[2], h[3]),
                                 pack2(h[4], h[5]), pack2(h[6], h[7]));
        }
    }
}

// ======== layers 2/3: 8 lanes/node, plain loads, bf16 tables (unchanged) ========

// ---------------- layer 2: add-aggr + root + bias + relu ----------------
__global__ __launch_bounds__(256) void layer2_kernel(
        const uint2* __restrict__ off2, const u32* __restrict__ recs,
        const uint4* __restrict__ h1b,
        const float* __restrict__ w2, const float* __restrict__ root2,
        const float* __restrict__ b2, u32* __restrict__ h2b) {
    int gid = blockIdx.x * 256 + threadIdx.x;
    int n = gid >> 3, r = gid & 7;
    if (n >= NN) return;
    float acc[12];
#pragma unroll
    for (int j = 0; j < 12; j++) acc[j] = 0.0f;

    uint2 o = off2[n];
    u32 k0 = o.x, k1 = o.y;
    for (u32 k = k0 + r; k < k1; k += 8) {
        u32 rec = recs[k];
        u32 t = rec & 127u, s = (rec >> 7) & 0x1FFFFu;
        uint4 hw = h1b[s];
        float a0 = unlo(hw.x), a1 = unhi(hw.x), a2 = unlo(hw.y), a3 = unhi(hw.y);
        float a4 = unlo(hw.z), a5 = unhi(hw.z), a6 = unlo(hw.w), a7 = unhi(hw.w);
        const float* w = w2 + (size_t)t * 24;   // [4][2][3]
#pragma unroll
        for (int o2 = 0; o2 < 3; o2++) {
            acc[o2]     += a0 * w[o2]      + a1 * w[3 + o2];
            acc[3 + o2] += a2 * w[6 + o2]  + a3 * w[9 + o2];
            acc[6 + o2] += a4 * w[12 + o2] + a5 * w[15 + o2];
            acc[9 + o2] += a6 * w[18 + o2] + a7 * w[21 + o2];
        }
    }
#pragma unroll
    for (int j = 0; j < 12; j++) {
        acc[j] += __shfl_xor(acc[j], 1);
        acc[j] += __shfl_xor(acc[j], 2);
        acc[j] += __shfl_xor(acc[j], 4);
    }
    if (r != 0) return;
    uint4 hn = h1b[n];
    float hv[8] = { unlo(hn.x), unhi(hn.x), unlo(hn.y), unhi(hn.y),
                    unlo(hn.z), unhi(hn.z), unlo(hn.w), unhi(hn.w) };
    float h[12];
#pragma unroll
    for (int j = 0; j < 12; j++) {
        float v = acc[j] + b2[j];
#pragma unroll
        for (int i = 0; i < 8; i++) v += hv[i] * root2[i * 12 + j];
        h[j] = fmaxf(v, 0.0f);
    }
    u32* hb = h2b + (size_t)n * 8;             // 32B stride, 24B used
    *(uint4*)hb = make_uint4(pack2(h[0], h[1]), pack2(h[2], h[3]),
                             pack2(h[4], h[5]), pack2(h[6], h[7]));
    *(uint2*)(hb + 4) = make_uint2(pack2(h[8], h[9]), pack2(h[10], h[11]));
}

// ---------------- layer 3: mean-aggr + root + bias + log_softmax ----------------
__global__ __launch_bounds__(256) void layer3_kernel(
        const uint2* __restrict__ off2, const u32* __restrict__ recs,
        const u32* __restrict__ h2b,
        const float* __restrict__ w3, const float* __restrict__ root3,
        const float* __restrict__ b3, float* __restrict__ out) {
    int gid = blockIdx.x * 256 + threadIdx.x;
    int n = gid >> 3, r = gid & 7;
    if (n >= NN) return;
    float acc[4] = {0.0f, 0.0f, 0.0f, 0.0f};
    uint2 o = off2[n];
    u32 k0 = o.x, k1 = o.y;
    for (u32 k = k0 + r; k < k1; k += 8) {
        u32 rec = recs[k];
        u32 t = rec & 127u, s = (rec >> 7) & 0x1FFFFu;
        float norm = 1.0f / (float)(rec >> 24);
        const u32* hb = h2b + (size_t)s * 8;
        uint4 q = *(const uint4*)hb;
        uint2 p = *(const uint2*)(hb + 4);
        float hsv[12] = { unlo(q.x), unhi(q.x), unlo(q.y), unhi(q.y),
                          unlo(q.z), unhi(q.z), unlo(q.w), unhi(q.w),
                          unlo(p.x), unhi(p.x), unlo(p.y), unhi(p.y) };
        const float* w = w3 + (size_t)t * 24;   // [2][6][2]
        float m0 = 0.0f, m1 = 0.0f, m2 = 0.0f, m3 = 0.0f;
#pragma unroll
        for (int i = 0; i < 6; i++) {
            m0 += hsv[i] * w[i * 2];          m1 += hsv[i] * w[i * 2 + 1];
            m2 += hsv[6 + i] * w[12 + i * 2]; m3 += hsv[6 + i] * w[12 + i * 2 + 1];
        }
        acc[0] += m0 * norm; acc[1] += m1 * norm;
        acc[2] += m2 * norm; acc[3] += m3 * norm;
    }
#pragma unroll
    for (int j = 0; j < 4; j++) {
        acc[j] += __shfl_xor(acc[j], 1);
        acc[j] += __shfl_xor(acc[j], 2);
        acc[j] += __shfl_xor(acc[j], 4);
    }
    if (r != 0) return;
    const u32* hbn = h2b + (size_t)n * 8;
    uint4 qn = *(const uint4*)hbn; uint2 pn = *(const uint2*)(hbn + 4);
    float hv[12] = { unlo(qn.x), unhi(qn.x), unlo(qn.y), unhi(qn.y),
                     unlo(qn.z), unhi(qn.z), unlo(qn.w), unhi(qn.w),
                     unlo(pn.x), unhi(pn.x), unlo(pn.y), unhi(pn.y) };
    float t4[4];
#pragma unroll
    for (int j = 0; j < 4; j++) {
        float v = acc[j] + b3[j];
#pragma unroll
        for (int i = 0; i < 12; i++) v += hv[i] * root3[i * 4 + j];
        t4[j] = v;
    }
    float m = fmaxf(fmaxf(t4[0], t4[1]), fmaxf(t4[2], t4[3]));
    float s = 0.0f;
#pragma unroll
    for (int j = 0; j < 4; j++) s += __expf(t4[j] - m);
    float lse = m + __logf(s);
    *(float4*)(out + (size_t)n * 4) =
        make_float4(t4[0] - lse, t4[1] - lse, t4[2] - lse, t4[3] - lse);
}

extern "C" void kernel_launch(void* const* d_in, const int* in_sizes, int n_in,
                              void* d_out, int out_size, void* d_ws, size_t ws_size,
                              hipStream_t stream) {
    const float* x     = (const float*)d_in[0];
    const int*   ei    = (const int*)d_in[1];   // [2, E]
    const int*   etype = (const int*)d_in[2];
    const float* w1    = (const float*)d_in[3];
    const float* root1 = (const float*)d_in[4];
    const float* b1    = (const float*)d_in[5];
    const float* w2    = (const float*)d_in[6];
    const float* root2 = (const float*)d_in[7];
    const float* b2    = (const float*)d_in[8];
    const float* w3    = (const float*)d_in[9];
    const float* root3 = (const float*)d_in[10];
    const float* b3    = (const float*)d_in[11];
    float* out = (float*)d_out;

    const int* src = ei;
    const int* dst = ei + NE;

    // workspace layout (bytes):
    //   ccursor : [NB]      u32   @ 0           (pad 1,600)
    //   off2    : [NN]      uint2 @ 1,600       (800,000 -> pad 801,664)
    //   tmp     : [NB*CAP]  u32   @ 801,664     (19,218,432 -> pad 20,020,224)
    //   recs    : [NB*CAP]  u32   @ 20,020,224  (19,218,432 -> ends 39,238,656)
    //   h1b     : [NN]      16B   @ 39,238,656  ( 1,600,000)
    //   h2b     : [NN]      32B   @ 40,838,656  ( 3,200,000)  -> total 44,038,656
    char* ws = (char*)d_ws;
    u32*   ccursor = (u32*)ws;
    uint2* off2    = (uint2*)(ws + 1600);
    u32*   tmp     = (u32*)(ws + 801664);
    u32*   recs    = (u32*)(ws + 20020224);
    uint4* h1b     = (uint4*)(ws + 39238656);
    u32*   h2b     = (u32*)(ws + 40838656);

    hipMemsetAsync(ccursor, 0, NB * sizeof(u32), stream);

    dim3 pgrid(NCHUNK);                      // 782
    dim3 ngrid(NB);                          // 391
    dim3 lgrid((NN * 8 + 255) / 256);        // 3125 (8 lanes/node)

    pass1_kernel<<<pgrid, 512, 0, stream>>>(src, dst, etype, ccursor, tmp);
    pass2_kernel<<<ngrid, 1024, 0, stream>>>(tmp, ccursor, off2, recs, x, w1, root1, b1, h1b);
    layer2_kernel<<<lgrid, 256, 0, stream>>>(off2, recs, h1b, w2, root2, b2, h2b);
    layer3_kernel<<<lgrid, 256, 0, stream>>>(off2, recs, h2b, w3, root3, b3, out);
}

// Round 19
// 262.960 us; speedup vs baseline: 1.0557x; 1.0557x over previous
//
#include <hip/hip_runtime.h>
#include <math.h>

#define NN 100000
#define NE 3200000
#define NR 90
#define NB 391          // buckets of 256 nodes (dst>>8)
#define CH 4096         // edges per block in pass1
#define NCHUNK 782      // ceil(NE/CH)
#define CAP 12288       // padded per-bucket capacity (mean 8192, +45 sigma)

typedef unsigned int u32;
typedef unsigned short u16;

__device__ inline u32 pack2(float a, float b) {       // bf16(a) lo16, bf16(b) hi16 (RNE)
    u32 ua = __float_as_uint(a); ua += 0x7FFFu + ((ua >> 16) & 1u);
    u32 ub = __float_as_uint(b); ub += 0x7FFFu + ((ub >> 16) & 1u);
    return (ua >> 16) | (ub & 0xFFFF0000u);
}
__device__ inline float unlo(u32 w) { return __uint_as_float(w << 16); }
__device__ inline float unhi(u32 w) { return __uint_as_float(w & 0xFFFF0000u); }

// ---------------- pass 1: direct padded-bucket partition (no pre-count) ----------------
// tmp entry: (dst&255)<<24 | src<<7 | et ; bucket b's window is tmp[b*CAP ..]
__global__ __launch_bounds__(512) void pass1_kernel(const int* __restrict__ src,
                                                    const int* __restrict__ dst,
                                                    const int* __restrict__ et,
                                                    u32* __restrict__ ccursor,
                                                    u32* __restrict__ tmp) {
    __shared__ u32 cntA[NB];
    __shared__ u32 lcur[NB];
    __shared__ u32 delta[NB];
    __shared__ u32 scanS[512];
    __shared__ u32 lrecs[CH];
    __shared__ u16 lbid[CH];
    int tid = threadIdx.x;
    int c0 = blockIdx.x * CH;
    int c1 = c0 + CH; if (c1 > NE) c1 = NE;
    int nloc = c1 - c0;

    if (tid < NB) cntA[tid] = 0;
    __syncthreads();

    for (int e = c0 + tid; e < c1; e += 512)
        atomicAdd(&cntA[(u32)dst[e] >> 8], 1u);
    __syncthreads();

    scanS[tid] = (tid < NB) ? cntA[tid] : 0u;
    __syncthreads();
#pragma unroll
    for (int ofs = 1; ofs < 512; ofs <<= 1) {
        u32 v = (tid >= ofs) ? scanS[tid - ofs] : 0u;
        __syncthreads();
        scanS[tid] += v;
        __syncthreads();
    }
    if (tid < NB) {
        u32 excl = (tid == 0) ? 0u : scanS[tid - 1];
        lcur[tid] = excl;
        u32 c = cntA[tid];
        delta[tid] = c ? ((u32)tid * CAP + atomicAdd(&ccursor[tid], c) - excl) : 0u;
    }
    __syncthreads();

    for (int e = c0 + tid; e < c1; e += 512) {
        u32 d = (u32)dst[e];
        u32 b = d >> 8;
        u32 pos = atomicAdd(&lcur[b], 1u);
        lrecs[pos] = ((d & 255u) << 24) | ((u32)src[e] << 7) | (u32)et[e];
        lbid[pos] = (u16)b;
    }
    __syncthreads();

    for (int k = tid; k < nloc; k += 512)
        tmp[delta[lbid[k]] + k] = lrecs[k];
}

// ---------------- pass 2 + layer 1 fused (1024 threads/block) ----------------
// A': per-(node,rel) counts, tmp register-cached (1 LDS atomic/edge, single tmp read);
// B: degrees by byte-sum + scan; C: scatter final recs with cnt embedded (no phase D);
// E: layer1.
__global__ __launch_bounds__(1024) void pass2_kernel(const u32* __restrict__ tmp,
                                                     const u32* __restrict__ ccursor,
                                                     uint2* __restrict__ off2,
                                                     u32* __restrict__ recs,
                                                     const float* __restrict__ x,
                                                     const float* __restrict__ w1,
                                                     const float* __restrict__ root1,
                                                     const float* __restrict__ b1,
                                                     uint4* __restrict__ h1b) {
    __shared__ u32 lc2[256];         // per-node cursor (relative)
    __shared__ u32 cnt32[256 * 23];  // per-(node,rel) u8 counts packed 4/word
    __shared__ u32 sh[256];          // inclusive degree scan (survives all phases)
    int tid = threadIdx.x;
    int b = blockIdx.x;
    u32 r0 = (u32)b * CAP;
    u32 r1 = r0 + ccursor[b];        // cursor's final value == bucket edge count

    for (int i = tid; i < 256 * 23; i += 1024) cnt32[i] = 0;
    __syncthreads();

    // A': single tmp read, register-cached; one LDS atomic per edge
    u32 cached[12];                  // CAP/1024 = 12 max entries per thread
#pragma unroll
    for (int i = 0; i < 12; i++) {
        u32 k = r0 + tid + (u32)i * 1024u;
        u32 v = (k < r1) ? tmp[k] : 0xFFFFFFFFu;
        cached[i] = v;
        if (k < r1) {
            u32 ln = v >> 24, rel = v & 127u;
            atomicAdd(&cnt32[ln * 23 + (rel >> 2)], 1u << ((rel & 3u) * 8u));
        }
    }
    __syncthreads();

    // A2: per-node degree = bytewise sum of own 23-word slice (no atomics)
    if (tid < 256) {
        u32 s = 0;
#pragma unroll
        for (int i = 0; i < 23; i++) {
            u32 w = cnt32[tid * 23 + i];
            s += (w & 255u) + ((w >> 8) & 255u) + ((w >> 16) & 255u) + (w >> 24);
        }
        sh[tid] = s;
    }
    __syncthreads();

    // B: inclusive scan of degrees (256 entries)
#pragma unroll
    for (int ofs = 1; ofs < 256; ofs <<= 1) {
        u32 v = (tid >= ofs && tid < 256) ? sh[tid - ofs] : 0u;
        __syncthreads();
        if (tid < 256) sh[tid] += v;
        __syncthreads();
    }
    int n = b * 256 + tid;
    if (tid < 256) {
        u32 excl = (tid == 0) ? 0u : sh[tid - 1];
        if (n < NN) off2[n] = make_uint2(r0 + excl, r0 + sh[tid]);
        lc2[tid] = excl;
    }
    __syncthreads();

    // C: scatter final recs — cnt32 is complete, so embed count byte here (no phase D)
#pragma unroll
    for (int i = 0; i < 12; i++) {
        u32 k = r0 + tid + (u32)i * 1024u;
        if (k < r1) {
            u32 v = cached[i];
            u32 ln = v >> 24, rel = v & 127u;
            u32 c = (cnt32[ln * 23 + (rel >> 2)] >> ((rel & 3u) * 8u)) & 255u;
            u32 pos = atomicAdd(&lc2[ln], 1u);
            recs[r0 + pos] = (c << 24) | (v & 0xFFFFFFu);
        }
    }
    __syncthreads();

    // E: layer 1 for this bucket's 256 nodes — 8 lanes/node, 2 sweeps of 128 nodes
#pragma unroll
    for (int g = 0; g < 2; g++) {
        int ln = g * 128 + (tid >> 3);         // 0..255
        int r = tid & 7;
        int nn = b * 256 + ln;
        float acc[8];
#pragma unroll
        for (int j = 0; j < 8; j++) acc[j] = 0.0f;
        if (nn < NN) {
            u32 k0 = r0 + ((ln == 0) ? 0u : sh[ln - 1]);
            u32 k1 = r0 + sh[ln];
            for (u32 k = k0 + r; k < k1; k += 8) {
                u32 rec = recs[k];
                u32 t = rec & 127u, s = (rec >> 7) & 0x1FFFFu;
                float norm = 1.0f / (float)(rec >> 24);
                float4 xv = *(const float4*)(x + (size_t)s * 4);
                float x0 = xv.x * norm, x1 = xv.y * norm;
                float x2 = xv.z * norm, x3 = xv.w * norm;
                const float* w = w1 + (size_t)t * 16;   // [2][2][4]
#pragma unroll
                for (int o = 0; o < 4; o++) {
                    acc[o]     += x0 * w[o]     + x1 * w[4 + o];
                    acc[4 + o] += x2 * w[8 + o] + x3 * w[12 + o];
                }
            }
        }
#pragma unroll
        for (int j = 0; j < 8; j++) {
            acc[j] += __shfl_xor(acc[j], 1);
            acc[j] += __shfl_xor(acc[j], 2);
            acc[j] += __shfl_xor(acc[j], 4);
        }
        if (r == 0 && nn < NN) {
            float4 xn = *(const float4*)(x + (size_t)nn * 4);
            float h[8];
#pragma unroll
            for (int j = 0; j < 8; j++) {
                float v = acc[j] + b1[j] + xn.x * root1[j] + xn.y * root1[8 + j]
                        + xn.z * root1[16 + j] + xn.w * root1[24 + j];
                h[j] = fmaxf(v, 0.0f);
            }
            h1b[nn] = make_uint4(pack2(h[0], h[1]), pack2(h[2], h[3]),
                                 pack2(h[4], h[5]), pack2(h[6], h[7]));
        }
    }
}

// ======== layers 2/3: 8 lanes/node, plain loads, bf16 tables (unchanged) ========

// ---------------- layer 2: add-aggr + root + bias + relu ----------------
__global__ __launch_bounds__(256) void layer2_kernel(
        const uint2* __restrict__ off2, const u32* __restrict__ recs,
        const uint4* __restrict__ h1b,
        const float* __restrict__ w2, const float* __restrict__ root2,
        const float* __restrict__ b2, u32* __restrict__ h2b) {
    int gid = blockIdx.x * 256 + threadIdx.x;
    int n = gid >> 3, r = gid & 7;
    if (n >= NN) return;
    float acc[12];
#pragma unroll
    for (int j = 0; j < 12; j++) acc[j] = 0.0f;

    uint2 o = off2[n];
    u32 k0 = o.x, k1 = o.y;
    for (u32 k = k0 + r; k < k1; k += 8) {
        u32 rec = recs[k];
        u32 t = rec & 127u, s = (rec >> 7) & 0x1FFFFu;
        uint4 hw = h1b[s];
        float a0 = unlo(hw.x), a1 = unhi(hw.x), a2 = unlo(hw.y), a3 = unhi(hw.y);
        float a4 = unlo(hw.z), a5 = unhi(hw.z), a6 = unlo(hw.w), a7 = unhi(hw.w);
        const float* w = w2 + (size_t)t * 24;   // [4][2][3]
#pragma unroll
        for (int o2 = 0; o2 < 3; o2++) {
            acc[o2]     += a0 * w[o2]      + a1 * w[3 + o2];
            acc[3 + o2] += a2 * w[6 + o2]  + a3 * w[9 + o2];
            acc[6 + o2] += a4 * w[12 + o2] + a5 * w[15 + o2];
            acc[9 + o2] += a6 * w[18 + o2] + a7 * w[21 + o2];
        }
    }
#pragma unroll
    for (int j = 0; j < 12; j++) {
        acc[j] += __shfl_xor(acc[j], 1);
        acc[j] += __shfl_xor(acc[j], 2);
        acc[j] += __shfl_xor(acc[j], 4);
    }
    if (r != 0) return;
    uint4 hn = h1b[n];
    float hv[8] = { unlo(hn.x), unhi(hn.x), unlo(hn.y), unhi(hn.y),
                    unlo(hn.z), unhi(hn.z), unlo(hn.w), unhi(hn.w) };
    float h[12];
#pragma unroll
    for (int j = 0; j < 12; j++) {
        float v = acc[j] + b2[j];
#pragma unroll
        for (int i = 0; i < 8; i++) v += hv[i] * root2[i * 12 + j];
        h[j] = fmaxf(v, 0.0f);
    }
    u32* hb = h2b + (size_t)n * 8;             // 32B stride, 24B used
    *(uint4*)hb = make_uint4(pack2(h[0], h[1]), pack2(h[2], h[3]),
                             pack2(h[4], h[5]), pack2(h[6], h[7]));
    *(uint2*)(hb + 4) = make_uint2(pack2(h[8], h[9]), pack2(h[10], h[11]));
}

// ---------------- layer 3: mean-aggr + root + bias + log_softmax ----------------
__global__ __launch_bounds__(256) void layer3_kernel(
        const uint2* __restrict__ off2, const u32* __restrict__ recs,
        const u32* __restrict__ h2b,
        const float* __restrict__ w3, const float* __restrict__ root3,
        const float* __restrict__ b3, float* __restrict__ out) {
    int gid = blockIdx.x * 256 + threadIdx.x;
    int n = gid >> 3, r = gid & 7;
    if (n >= NN) return;
    float acc[4] = {0.0f, 0.0f, 0.0f, 0.0f};
    uint2 o = off2[n];
    u32 k0 = o.x, k1 = o.y;
    for (u32 k = k0 + r; k < k1; k += 8) {
        u32 rec = recs[k];
        u32 t = rec & 127u, s = (rec >> 7) & 0x1FFFFu;
        float norm = 1.0f / (float)(rec >> 24);
        const u32* hb = h2b + (size_t)s * 8;
        uint4 q = *(const uint4*)hb;
        uint2 p = *(const uint2*)(hb + 4);
        float hsv[12] = { unlo(q.x), unhi(q.x), unlo(q.y), unhi(q.y),
                          unlo(q.z), unhi(q.z), unlo(q.w), unhi(q.w),
                          unlo(p.x), unhi(p.x), unlo(p.y), unhi(p.y) };
        const float* w = w3 + (size_t)t * 24;   // [2][6][2]
        float m0 = 0.0f, m1 = 0.0f, m2 = 0.0f, m3 = 0.0f;
#pragma unroll
        for (int i = 0; i < 6; i++) {
            m0 += hsv[i] * w[i * 2];          m1 += hsv[i] * w[i * 2 + 1];
            m2 += hsv[6 + i] * w[12 + i * 2]; m3 += hsv[6 + i] * w[12 + i * 2 + 1];
        }
        acc[0] += m0 * norm; acc[1] += m1 * norm;
        acc[2] += m2 * norm; acc[3] += m3 * norm;
    }
#pragma unroll
    for (int j = 0; j < 4; j++) {
        acc[j] += __shfl_xor(acc[j], 1);
        acc[j] += __shfl_xor(acc[j], 2);
        acc[j] += __shfl_xor(acc[j], 4);
    }
    if (r != 0) return;
    const u32* hbn = h2b + (size_t)n * 8;
    uint4 qn = *(const uint4*)hbn; uint2 pn = *(const uint2*)(hbn + 4);
    float hv[12] = { unlo(qn.x), unhi(qn.x), unlo(qn.y), unhi(qn.y),
                     unlo(qn.z), unhi(qn.z), unlo(qn.w), unhi(qn.w),
                     unlo(pn.x), unhi(pn.x), unlo(pn.y), unhi(pn.y) };
    float t4[4];
#pragma unroll
    for (int j = 0; j < 4; j++) {
        float v = acc[j] + b3[j];
#pragma unroll
        for (int i = 0; i < 12; i++) v += hv[i] * root3[i * 4 + j];
        t4[j] = v;
    }
    float m = fmaxf(fmaxf(t4[0], t4[1]), fmaxf(t4[2], t4[3]));
    float s = 0.0f;
#pragma unroll
    for (int j = 0; j < 4; j++) s += __expf(t4[j] - m);
    float lse = m + __logf(s);
    *(float4*)(out + (size_t)n * 4) =
        make_float4(t4[0] - lse, t4[1] - lse, t4[2] - lse, t4[3] - lse);
}

extern "C" void kernel_launch(void* const* d_in, const int* in_sizes, int n_in,
                              void* d_out, int out_size, void* d_ws, size_t ws_size,
                              hipStream_t stream) {
    const float* x     = (const float*)d_in[0];
    const int*   ei    = (const int*)d_in[1];   // [2, E]
    const int*   etype = (const int*)d_in[2];
    const float* w1    = (const float*)d_in[3];
    const float* root1 = (const float*)d_in[4];
    const float* b1    = (const float*)d_in[5];
    const float* w2    = (const float*)d_in[6];
    const float* root2 = (const float*)d_in[7];
    const float* b2    = (const float*)d_in[8];
    const float* w3    = (const float*)d_in[9];
    const float* root3 = (const float*)d_in[10];
    const float* b3    = (const float*)d_in[11];
    float* out = (float*)d_out;

    const int* src = ei;
    const int* dst = ei + NE;

    // workspace layout (bytes):
    //   ccursor : [NB]      u32   @ 0           (pad 1,600)
    //   off2    : [NN]      uint2 @ 1,600       (800,000 -> pad 801,664)
    //   tmp     : [NB*CAP]  u32   @ 801,664     (19,218,432 -> pad 20,020,224)
    //   recs    : [NB*CAP]  u32   @ 20,020,224  (19,218,432 -> ends 39,238,656)
    //   h1b     : [NN]      16B   @ 39,238,656  ( 1,600,000)
    //   h2b     : [NN]      32B   @ 40,838,656  ( 3,200,000)  -> total 44,038,656
    char* ws = (char*)d_ws;
    u32*   ccursor = (u32*)ws;
    uint2* off2    = (uint2*)(ws + 1600);
    u32*   tmp     = (u32*)(ws + 801664);
    u32*   recs    = (u32*)(ws + 20020224);
    uint4* h1b     = (uint4*)(ws + 39238656);
    u32*   h2b     = (u32*)(ws + 40838656);

    hipMemsetAsync(ccursor, 0, NB * sizeof(u32), stream);

    dim3 pgrid(NCHUNK);                      // 782
    dim3 ngrid(NB);                          // 391
    dim3 lgrid((NN * 8 + 255) / 256);        // 3125 (8 lanes/node)

    pass1_kernel<<<pgrid, 512, 0, stream>>>(src, dst, etype, ccursor, tmp);
    pass2_kernel<<<ngrid, 1024, 0, stream>>>(tmp, ccursor, off2, recs, x, w1, root1, b1, h1b);
    layer2_kernel<<<lgrid, 256, 0, stream>>>(off2, recs, h1b, w2, root2, b2, h2b);
    layer3_kernel<<<lgrid, 256, 0, stream>>>(off2, recs, h2b, w3, root3, b3, out);
}